// Round 16
// baseline (104114.368 us; speedup 1.0000x reference)
//
#include <hip/hip_runtime.h>
#include <stdint.h>

#define VOCAB 60
#define EMB   100
#define HID   100
#define SEQN  262144
#define NPROJ 300     // 3*HID
#define HSTR  104     // h halves in LDS (100 used, 8B-aligned stride)
#define NW    8       // waves (2 per SIMD)
#define MT    3       // M-tiles per wave: one per gate (r,z,n), j = 16w + rho
#define KS    3       // MFMA K-steps (k<96); k in [96,100) handled by VALU tail

typedef float    f32x4 __attribute__((ext_vector_type(4)));
typedef _Float16 h16x2 __attribute__((ext_vector_type(2)));
typedef _Float16 h16x4 __attribute__((ext_vector_type(4)));
typedef _Float16 h16x8 __attribute__((ext_vector_type(8)));

__device__ __forceinline__ float fast_sig(float x) {
    return __builtin_amdgcn_rcpf(1.0f + __builtin_amdgcn_exp2f(-1.442695041f * x));
}
__device__ __forceinline__ float fast_tanh(float x) {
    return 2.0f * __builtin_amdgcn_rcpf(1.0f + __builtin_amdgcn_exp2f(-2.885390082f * x)) - 1.0f;
}

#if __has_builtin(__builtin_amdgcn_fdot2)
#define DOT2(A, B, C) __builtin_amdgcn_fdot2((A), (B), (C), false)
#else
__device__ __forceinline__ float DOT2(h16x2 a, h16x2 b, float c) {
    return fmaf((float)a.x, (float)b.x, fmaf((float)a.y, (float)b.y, c));
}
#endif

#define AS2(U)    __builtin_bit_cast(h16x2, (U))
#define SH2(V, I) __builtin_shufflevector((V), (V), (I), (I) + 1)

// Job 1: proj[v][j] = emb[v]·w_ih[j] + b_ih[j] + (j<200 ? b_hh[j] : 0)  (fp32)
// Job 2: afrag = W_hh in 8-wave MFMA A-fragment order (f16, zero-padded):
//   wave w (0..7), tile m (0..2: gate wh=m), A-row rho=lane&15:
//     j = 16w + rho, W-row = wh*100 + j (pad if j>=100; wave 7 all padding)
//   k = ks*32 + (lane>>4)*8 + e   (KS=3, k<96)
// Job 3: wtail[(g*HID+j)*4+e] = w_hh[(g*HID+j)*HID + 96 + e]  (k-tail weights)
__global__ void precompute_kernel(const float* __restrict__ emb,
                                  const float* __restrict__ w_ih,
                                  const float* __restrict__ b_ih,
                                  const float* __restrict__ b_hh,
                                  const float* __restrict__ w_hh,
                                  float* __restrict__ proj,
                                  _Float16* __restrict__ afrag,
                                  _Float16* __restrict__ wtail)
{
    int idx = blockIdx.x * blockDim.x + threadIdx.x;
    if (idx < VOCAB * NPROJ) {
        int v = idx / NPROJ, j = idx - v * NPROJ;
        float acc = b_ih[j] + (j < 2 * HID ? b_hh[j] : 0.0f);
        const float* er = emb  + v * EMB;
        const float* wr = w_ih + j * EMB;
        #pragma unroll 4
        for (int k = 0; k < EMB; ++k) acc = fmaf(er[k], wr[k], acc);
        proj[idx] = acc;
    }
    if (idx < NW * MT * KS * 64 * 8) {        // 36864 halves
        int e    = idx & 7;
        int lane = (idx >> 3) & 63;
        int q0   = idx >> 9;
        int ks   = q0 % KS;
        int q1   = q0 / KS;
        int m    = q1 % MT;
        int w    = q1 / MT;
        int j    = 16 * w + (lane & 15);
        int k    = ks * 32 + ((lane >> 4) << 3) + e;
        afrag[idx] = (j < HID)
                   ? (_Float16)w_hh[(m * HID + j) * HID + k] : (_Float16)0.0f;
    }
    if (idx < 3 * HID * 4) {                  // 1200 halves
        int e = idx & 3;
        int row = idx >> 2;                   // g*HID + j
        wtail[idx] = (_Float16)w_hh[row * HID + 96 + e];
    }
}

#define MFMA(A, B, C) __builtin_amdgcn_mfma_f32_16x16x32_f16((A), (B), (C), 0, 0, 0)

#define LOADF(M, K) \
    h16x8 af_##M##_##K = *(const h16x8*)(afrag + ((((wave*MT+(M))*KS+(K))*64) + lane) * 8);

// v_mov pin: opaque definition -> not rematerializable (r8-proven).
#define PIN(D) asm("v_mov_b32 %0, %0" : "+v"(D));

// Cheap barrier: drain LDS only; leave global prefetch (vmcnt) in flight.
#define BAR() asm volatile("s_waitcnt lgkmcnt(0)\n\ts_barrier" ::: "memory")

// B-prep for next step: 3 broadcast b128 (k<96) + 1 broadcast b64 (k-tail).
#define B_LOAD(BUF) {                                   \
    const _Float16* hp_ = hbuf[BUF];                    \
    b0  = *(const h16x8*)(hp_ +  0 + ko);               \
    b1  = *(const h16x8*)(hp_ + 32 + ko);               \
    b2  = *(const h16x8*)(hp_ + 64 + ko);               \
    hb4 = *(const h16x4*)(hp_ + 96); }

// f32x4 -> scalar select by qs=c&3 (compile-time element indices; 3 cndmask).
#define MUX(AC, S) {                                    \
    float lo_ = (qs & 1) ? AC[1] : AC[0];               \
    float hi_ = (qs & 1) ? AC[3] : AC[2];               \
    S = (qs & 2) ? hi_ : lo_; }

// One GRU step. CUR/NXT compile-time buffer indices; TOKSRC = token of step t+1.
// Gate-ordered: R chain -> R gate -> Z chain -> Z gate -> N chain -> N tail.
#define STEP(CUR, NXT, TOKSRC) {                                            \
    /* pins: loop-carried AGPR fragments, consumed in place by MFMA */      \
    asm("" : "+a"(af_0_0), "+a"(af_0_1), "+a"(af_0_2), "+a"(af_1_0), "+a"(af_1_1)); \
    asm("" : "+a"(af_1_2), "+a"(af_2_0), "+a"(af_2_1), "+a"(af_2_2));       \
    /* proj prefetch for step t+1 (scalar token, SALU-scaled base) */       \
    int ts_ = __builtin_amdgcn_readfirstlane(TOKSRC);                       \
    const float* pb_ = projj + ts_ * NPROJ;                                 \
    float xr_n = pb_[0];                                                    \
    float xz_n = pb_[HID];                                                  \
    float xn_n = pb_[2 * HID];                                              \
    h16x2 hb01 = SH2(hb4, 0), hb23 = SH2(hb4, 2);                           \
    /* R chain (tile 0) + R gate (hides under Z/N chains) */                \
    f32x4 ac0;                                                              \
    ac0 = MFMA(af_0_0, b0, zz);                                             \
    ac0 = MFMA(af_0_1, b1, ac0);                                            \
    ac0 = MFMA(af_0_2, b2, ac0);                                            \
    float sR; MUX(ac0, sR)                                                  \
    float tR  = DOT2(AS2(wtR01), hb01, DOT2(AS2(wtR23), hb23, 0.0f));       \
    float r   = fast_sig(sR + tR + xr);                                     \
    /* Z chain (tile 1) + Z gate */                                         \
    f32x4 ac1;                                                              \
    ac1 = MFMA(af_1_0, b0, zz);                                             \
    ac1 = MFMA(af_1_1, b1, ac1);                                            \
    ac1 = MFMA(af_1_2, b2, ac1);                                            \
    float sZ; MUX(ac1, sZ)                                                  \
    float tZ  = DOT2(AS2(wtZ01), hb01, DOT2(AS2(wtZ23), hb23, 0.0f));       \
    float z   = fast_sig(sZ + tZ + xz);                                     \
    /* N chain (tile 2) + serial tail */                                    \
    f32x4 ac2;                                                              \
    ac2 = MFMA(af_2_0, b0, zz);                                             \
    ac2 = MFMA(af_2_1, b1, ac2);                                            \
    ac2 = MFMA(af_2_2, b2, ac2);                                            \
    float sN; MUX(ac2, sN)                                                  \
    float tN  = DOT2(AS2(wtN01), hb01, DOT2(AS2(wtN23), hb23, 0.0f));       \
    float n   = fast_tanh(xn + r * (sN + tN + bhn));                        \
    float hnew = n + z * (hold - n);                                        \
    hold = hnew;                                                            \
    if (active) hbuf[NXT][j] = (_Float16)hnew;                              \
    BAR();                                                                  \
    B_LOAD(NXT);            /* pipelined B-prep for the next step */        \
    xr = xr_n;  xz = xz_n;  xn = xn_n; }

// 512 threads = 8 waves = 2/SIMD. Wave w owns j in [16w,16w+16): 9 MFMA
// (3 tiles x KS=3; wave 7 = padding, kept for SIMD balance) produce its
// (r,z,n) u-triples in registers; active lanes (G==c>>2) mux with 3 cndmask
// (q=c&3), run the gate chain, publish h_j. Two waves/SIMD interleave so
// MFMA-wait of one hides under VALU of the other — the r15 single-wave
// issue-serialization fix. ONE cheap barrier/step; B-prep pipelined;
// unroll x4 with quad token queue.
__global__ __launch_bounds__(512, 2) __attribute__((amdgpu_waves_per_eu(2, 2)))
void gru_seq_kernel(const int*      __restrict__ x,
                    const float*    __restrict__ b_hh,
                    const float*    __restrict__ proj,
                    const _Float16* __restrict__ afrag,
                    const _Float16* __restrict__ wtail,
                    float*          __restrict__ out)
{
    __shared__ __align__(16) _Float16 hbuf[2][HSTR];

    const int tid  = threadIdx.x;
    const int wave = tid >> 6;
    const int lane = tid & 63;
    const int G    = lane >> 4;
    const int c    = lane & 15;
    const int ko   = G << 3;                           // B k-slice offset
    const int qs   = c & 3;                            // C/D reg selector

    const int  jv     = 16 * wave + c;
    const bool active = (G == (c >> 2)) && (jv < HID); // lane owns D-row c
    const int  j      = active ? jv : 0;

    if (tid < 2 * HSTR) ((_Float16*)hbuf)[tid] = (_Float16)0.0f;

    // 9 A fragments (36 AGPR dwords), AGPR-parked.
    LOADF(0,0) LOADF(0,1) LOADF(0,2)
    LOADF(1,0) LOADF(1,1) LOADF(1,2)
    LOADF(2,0) LOADF(2,1) LOADF(2,2)

    // k-tail weights for this lane's j: 3 gates x 4 halves = 6 pinned dwords.
    const uint32_t* wt32 = (const uint32_t*)wtail;
    uint32_t wtR01 = wt32[(0 * HID + j) * 2],     wtR23 = wt32[(0 * HID + j) * 2 + 1];
    uint32_t wtZ01 = wt32[(1 * HID + j) * 2],     wtZ23 = wt32[(1 * HID + j) * 2 + 1];
    uint32_t wtN01 = wt32[(2 * HID + j) * 2],     wtN23 = wt32[(2 * HID + j) * 2 + 1];
    PIN(wtR01) PIN(wtR23) PIN(wtZ01) PIN(wtZ23) PIN(wtN01) PIN(wtN23)

    const float  bhn   = b_hh[2 * HID + j];
    const float* projj = proj + j;                     // per-lane base, invariant
    float hold = 0.0f;

    // Token quad queue: qA = x[t..t+3], qB = x[t+4..t+7] (aligned int4 loads).
    int4 qA = *(const int4*)(x);
    int4 qB = *(const int4*)(x + 4);

    // Pipeline init: step 0 proj from token 0.
    int tok0 = __builtin_amdgcn_readfirstlane(qA.x);
    float xr = projj[tok0 * NPROJ];
    float xz = projj[tok0 * NPROJ + HID];
    float xn = projj[tok0 * NPROJ + 2 * HID];

    const f32x4 zz = {0.f, 0.f, 0.f, 0.f};
    h16x8 b0, b1, b2;
    h16x4 hb4;
    __syncthreads();
    B_LOAD(0);                                         // prologue B-prep

    for (int t = 0; t < SEQN; t += 4) {
        // Load the quad for steps t+8..t+11 (clamped near the end; uniform).
        int  ldix = (t + 8 <= SEQN - 4) ? (t + 8) : (SEQN - 4);
        int4 qC   = *(const int4*)(x + ldix);

        STEP(0, 1, qA.y)     // step t   : prefetch token t+1
        STEP(1, 0, qA.z)     // step t+1 : prefetch token t+2
        STEP(0, 1, qA.w)     // step t+2 : prefetch token t+3
        STEP(1, 0, qB.x)     // step t+3 : prefetch token t+4

        qA = qB;  qB = qC;
    }

    if (active) out[j] = hold;
}

extern "C" void kernel_launch(void* const* d_in, const int* in_sizes, int n_in,
                              void* d_out, int out_size, void* d_ws, size_t ws_size,
                              hipStream_t stream)
{
    const int*   x    = (const int*)  d_in[0];
    const float* emb  = (const float*)d_in[1];
    const float* w_ih = (const float*)d_in[2];
    const float* w_hh = (const float*)d_in[3];
    const float* b_ih = (const float*)d_in[4];
    const float* b_hh = (const float*)d_in[5];
    float* out = (float*)d_out;

    float*    proj  = (float*)d_ws;                        // 18000 f32 = 72 KB
    _Float16* afrag = (_Float16*)(proj + VOCAB * NPROJ);   // 36864 f16 = 72 KB
    _Float16* wtail = afrag + NW * MT * KS * 64 * 8;       // 1200 f16 = 2.4 KB

    const int total = NW * MT * KS * 64 * 8;               // 36864 covers all jobs
    precompute_kernel<<<(total + 255) / 256, 256, 0, stream>>>(
        emb, w_ih, b_ih, b_hh, w_hh, proj, afrag, wtail);
    gru_seq_kernel<<<1, 512, 0, stream>>>(x, b_hh, proj, afrag, wtail, out);
}

// Round 17
// 93990.082 us; speedup vs baseline: 1.1077x; 1.1077x over previous
//
#include <hip/hip_runtime.h>
#include <stdint.h>

#define VOCAB 60
#define EMB   100
#define HID   100
#define SEQN  262144
#define NPROJ 300     // 3*HID
#define HSTR  104     // h halves in LDS (100 used, 8B-aligned stride)
#define NMFW  4       // waves
#define MT    6       // M-tiles per wave (96 rows; triple-grouped)
#define KS    3       // MFMA K-steps (k<96); k in [96,100) handled by VALU tail

typedef float    f32x4 __attribute__((ext_vector_type(4)));
typedef _Float16 h16x2 __attribute__((ext_vector_type(2)));
typedef _Float16 h16x4 __attribute__((ext_vector_type(4)));
typedef _Float16 h16x8 __attribute__((ext_vector_type(8)));

__device__ __forceinline__ float fast_sig(float x) {
    return __builtin_amdgcn_rcpf(1.0f + __builtin_amdgcn_exp2f(-1.442695041f * x));
}
__device__ __forceinline__ float fast_tanh(float x) {
    return 2.0f * __builtin_amdgcn_rcpf(1.0f + __builtin_amdgcn_exp2f(-2.885390082f * x)) - 1.0f;
}

#if __has_builtin(__builtin_amdgcn_fdot2)
#define DOT2(A, B, C) __builtin_amdgcn_fdot2((A), (B), (C), false)
#else
__device__ __forceinline__ float DOT2(h16x2 a, h16x2 b, float c) {
    return fmaf((float)a.x, (float)b.x, fmaf((float)a.y, (float)b.y, c));
}
#endif

#define AS2(U)    __builtin_bit_cast(h16x2, (U))
#define SH2(V, I) __builtin_shufflevector((V), (V), (I), (I) + 1)

// Job 1: proj[v][j] = emb[v]·w_ih[j] + b_ih[j] + (j<200 ? b_hh[j] : 0)  (fp32)
// Job 2: afrag = W_hh in TRIPLE-GROUPED MFMA A-fragment order, KS=3 (k<96):
//   wave w, tile m, A-row rho=lane&15 (G=rho>>2, q=rho&3):
//     wh = m%3 (0=r,1=z,2=n), j = 32w + 8G + 2q + (m>=3), W-row = wh*100+j
//   k = ks*32 + (lane>>4)*8 + e            [r12/r14-verified]
// Job 3: wtail[(g*HID+j)*4+e] = w_hh[(g*HID+j)*HID + 96 + e]  (k-tail weights)
__global__ void precompute_kernel(const float* __restrict__ emb,
                                  const float* __restrict__ w_ih,
                                  const float* __restrict__ b_ih,
                                  const float* __restrict__ b_hh,
                                  const float* __restrict__ w_hh,
                                  float* __restrict__ proj,
                                  _Float16* __restrict__ afrag,
                                  _Float16* __restrict__ wtail)
{
    int idx = blockIdx.x * blockDim.x + threadIdx.x;
    if (idx < VOCAB * NPROJ) {
        int v = idx / NPROJ, j = idx - v * NPROJ;
        float acc = b_ih[j] + (j < 2 * HID ? b_hh[j] : 0.0f);
        const float* er = emb  + v * EMB;
        const float* wr = w_ih + j * EMB;
        #pragma unroll 4
        for (int k = 0; k < EMB; ++k) acc = fmaf(er[k], wr[k], acc);
        proj[idx] = acc;
    }
    if (idx < NMFW * MT * KS * 64 * 8) {      // 36864 halves
        int e    = idx & 7;
        int lane = (idx >> 3) & 63;
        int q0   = idx >> 9;
        int ks   = q0 % KS;
        int q1   = q0 / KS;
        int m    = q1 % MT;
        int w    = q1 / MT;
        int rho  = lane & 15;
        int G    = rho >> 2, q = rho & 3;
        int wh   = m % 3;
        int j    = 32 * w + 8 * G + 2 * q + (m >= 3 ? 1 : 0);
        int k    = ks * 32 + ((lane >> 4) << 3) + e;
        afrag[idx] = (j < HID)
                   ? (_Float16)w_hh[(wh * HID + j) * HID + k] : (_Float16)0.0f;
    }
    if (idx < 3 * HID * 4) {                  // 1200 halves
        int e = idx & 3;
        int row = idx >> 2;                   // g*HID + j
        wtail[idx] = (_Float16)w_hh[row * HID + 96 + e];
    }
}

#define MFMA(A, B, C) __builtin_amdgcn_mfma_f32_16x16x32_f16((A), (B), (C), 0, 0, 0)

#define LOADF(M, K) \
    h16x8 af_##M##_##K = *(const h16x8*)(afrag + ((((wave*MT+(M))*KS+(K))*64) + lane) * 8);

// v_mov pin: opaque definition -> not rematerializable (r8-proven).
#define PIN(D) asm("v_mov_b32 %0, %0" : "+v"(D));

// Cheap barrier: drain LDS only; leave global prefetch (vmcnt) in flight.
#define BAR() asm volatile("s_waitcnt lgkmcnt(0)\n\ts_barrier" ::: "memory")

// B-prep for next step: 3 broadcast b128 (k<96) + 1 broadcast b64 (k-tail).
#define B_LOAD(BUF) {                                   \
    const _Float16* hp_ = hbuf[BUF];                    \
    b0  = *(const h16x8*)(hp_ +  0 + ko);               \
    b1  = *(const h16x8*)(hp_ + 32 + ko);               \
    b2  = *(const h16x8*)(hp_ + 64 + ko);               \
    hb4 = *(const h16x4*)(hp_ + 96); }

// One GRU step. CUR/NXT compile-time buffer indices; TOKSRC = token of step t+1.
// Gate-ordered: R chains -> R gate -> Z chains -> Z gate -> N chains -> N tail.
// NEW (r17): accumulators pinned to arch VGPRs ("+v") right after each chain —
// v_mfma then writes D directly to VGPRs (gfx950 unified file), eliminating
// the per-element v_accvgpr_read traffic that dominated VALUBusy.
#define STEP(CUR, NXT, TOKSRC) {                                            \
    /* pins: loop-carried AGPR fragments, consumed in place by MFMA */      \
    asm("" : "+a"(af_0_0), "+a"(af_0_1), "+a"(af_0_2), "+a"(af_1_0), "+a"(af_1_1)); \
    asm("" : "+a"(af_1_2), "+a"(af_2_0), "+a"(af_2_1), "+a"(af_2_2), "+a"(af_3_0)); \
    asm("" : "+a"(af_3_1), "+a"(af_3_2), "+a"(af_4_0), "+a"(af_4_1), "+a"(af_4_2)); \
    asm("" : "+a"(af_5_0), "+a"(af_5_1), "+a"(af_5_2));                     \
    /* proj prefetch for step t+1 (scalar token, SALU-scaled base) */       \
    int ts_ = __builtin_amdgcn_readfirstlane(TOKSRC);                       \
    const float* pb_ = projj + ts_ * NPROJ;                                 \
    float xr_n = pb_[0];                                                    \
    float xz_n = pb_[HID];                                                  \
    float xn_n = pb_[2 * HID];                                              \
    h16x2 hb01 = SH2(hb4, 0), hb23 = SH2(hb4, 2);                           \
    /* R chains (tiles 0,3) */                                              \
    f32x4 ac0, ac3;                                                         \
    ac0 = MFMA(af_0_0, b0, zz);  ac3 = MFMA(af_3_0, b0, zz);                \
    ac0 = MFMA(af_0_1, b1, ac0); ac3 = MFMA(af_3_1, b1, ac3);               \
    ac0 = MFMA(af_0_2, b2, ac0); ac3 = MFMA(af_3_2, b2, ac3);               \
    asm("" : "+v"(ac0), "+v"(ac3));   /* D in VGPRs -> mux reads directly */ \
    /* R gate (runs in the shadow of Z/N MFMAs below) */                    \
    f32x4 acR = hi ? ac3 : ac0;                                             \
    float sRl = (q2 & 1) ? acR[1] : acR[0], sRh = (q2 & 1) ? acR[3] : acR[2]; \
    float sR  = (q2 & 2) ? sRh : sRl;                                       \
    float tR  = DOT2(AS2(wtR01), hb01, DOT2(AS2(wtR23), hb23, 0.0f));       \
    float r   = fast_sig(sR + tR + xr);                                     \
    /* Z chains (tiles 1,4) */                                              \
    f32x4 ac1, ac4;                                                         \
    ac1 = MFMA(af_1_0, b0, zz);  ac4 = MFMA(af_4_0, b0, zz);                \
    ac1 = MFMA(af_1_1, b1, ac1); ac4 = MFMA(af_4_1, b1, ac4);               \
    ac1 = MFMA(af_1_2, b2, ac1); ac4 = MFMA(af_4_2, b2, ac4);               \
    asm("" : "+v"(ac1), "+v"(ac4));                                         \
    f32x4 acZ = hi ? ac4 : ac1;                                             \
    float sZl = (q2 & 1) ? acZ[1] : acZ[0], sZh = (q2 & 1) ? acZ[3] : acZ[2]; \
    float sZ  = (q2 & 2) ? sZh : sZl;                                       \
    float tZ  = DOT2(AS2(wtZ01), hb01, DOT2(AS2(wtZ23), hb23, 0.0f));       \
    float z   = fast_sig(sZ + tZ + xz);                                     \
    /* N chains (tiles 2,5) */                                              \
    f32x4 ac2, ac5;                                                         \
    ac2 = MFMA(af_2_0, b0, zz);  ac5 = MFMA(af_5_0, b0, zz);                \
    ac2 = MFMA(af_2_1, b1, ac2); ac5 = MFMA(af_5_1, b1, ac5);               \
    ac2 = MFMA(af_2_2, b2, ac2); ac5 = MFMA(af_5_2, b2, ac5);               \
    asm("" : "+v"(ac2), "+v"(ac5));                                         \
    f32x4 acN = hi ? ac5 : ac2;                                             \
    float sNl = (q2 & 1) ? acN[1] : acN[0], sNh = (q2 & 1) ? acN[3] : acN[2]; \
    float sN  = (q2 & 2) ? sNh : sNl;                                       \
    float tN  = DOT2(AS2(wtN01), hb01, DOT2(AS2(wtN23), hb23, 0.0f));       \
    float n   = fast_tanh(xn + r * (sN + tN + bhn));                        \
    float hnew = n + z * (hold - n);                                        \
    hold = hnew;                                                            \
    if (active) hbuf[NXT][j] = (_Float16)hnew;                              \
    BAR();                                                                  \
    B_LOAD(NXT);            /* pipelined B-prep for the next step */        \
    xr = xr_n;  xz = xz_n;  xn = xn_n; }

// 256 threads = 4 waves (1/SIMD). Per wave: 18 MFMA (KS=3, gate-ordered) give
// (r,z,n) u-triples in VGPR-resident accumulators; dot2 tail covers k in
// [96,100); lane c<8 of each 16-lane group muxes its triple and runs the gate
// chain; R/Z gates hide under later MFMA chains. ONE cheap barrier/step;
// B-prep pipelined; unroll x4 with quad token queue.
__global__ __launch_bounds__(256, 1) __attribute__((amdgpu_waves_per_eu(1, 1)))
void gru_seq_kernel(const int*      __restrict__ x,
                    const float*    __restrict__ b_hh,
                    const float*    __restrict__ proj,
                    const _Float16* __restrict__ afrag,
                    const _Float16* __restrict__ wtail,
                    float*          __restrict__ out)
{
    __shared__ __align__(16) _Float16 hbuf[2][HSTR];

    const int tid  = threadIdx.x;
    const int wave = tid >> 6;
    const int lane = tid & 63;
    const int G    = lane >> 4;
    const int c    = lane & 15;
    const int ko   = (lane >> 4) << 3;                 // B k-slice offset

    const int  jv     = 32 * wave + 8 * G + c;         // valid when c<8
    const bool active = (c < 8) && (jv < HID);
    const int  j      = active ? jv : 0;
    const int  q2     = (c >> 1) & 3;                  // component selector
    const bool hi     = (c & 1);                       // tile-half selector

    if (tid < 2 * HSTR) ((_Float16*)hbuf)[tid] = (_Float16)0.0f;

    // 18 A fragments (72 AGPR dwords), AGPR-parked.
    LOADF(0,0) LOADF(0,1) LOADF(0,2)
    LOADF(1,0) LOADF(1,1) LOADF(1,2)
    LOADF(2,0) LOADF(2,1) LOADF(2,2)
    LOADF(3,0) LOADF(3,1) LOADF(3,2)
    LOADF(4,0) LOADF(4,1) LOADF(4,2)
    LOADF(5,0) LOADF(5,1) LOADF(5,2)

    // k-tail weights for this lane's j: 3 gates x 4 halves = 6 pinned dwords.
    const uint32_t* wt32 = (const uint32_t*)wtail;
    uint32_t wtR01 = wt32[(0 * HID + j) * 2],     wtR23 = wt32[(0 * HID + j) * 2 + 1];
    uint32_t wtZ01 = wt32[(1 * HID + j) * 2],     wtZ23 = wt32[(1 * HID + j) * 2 + 1];
    uint32_t wtN01 = wt32[(2 * HID + j) * 2],     wtN23 = wt32[(2 * HID + j) * 2 + 1];
    PIN(wtR01) PIN(wtR23) PIN(wtZ01) PIN(wtZ23) PIN(wtN01) PIN(wtN23)

    const float  bhn   = b_hh[2 * HID + j];
    const float* projj = proj + j;                     // per-lane base, invariant
    float hold = 0.0f;

    // Token quad queue: qA = x[t..t+3], qB = x[t+4..t+7] (aligned int4 loads).
    int4 qA = *(const int4*)(x);
    int4 qB = *(const int4*)(x + 4);

    // Pipeline init: step 0 proj from token 0.
    int tok0 = __builtin_amdgcn_readfirstlane(qA.x);
    float xr = projj[tok0 * NPROJ];
    float xz = projj[tok0 * NPROJ + HID];
    float xn = projj[tok0 * NPROJ + 2 * HID];

    const f32x4 zz = {0.f, 0.f, 0.f, 0.f};
    h16x8 b0, b1, b2;
    h16x4 hb4;
    __syncthreads();
    B_LOAD(0);                                         // prologue B-prep

    for (int t = 0; t < SEQN; t += 4) {
        // Load the quad for steps t+8..t+11 (clamped near the end; uniform).
        int  ldix = (t + 8 <= SEQN - 4) ? (t + 8) : (SEQN - 4);
        int4 qC   = *(const int4*)(x + ldix);

        STEP(0, 1, qA.y)     // step t   : prefetch token t+1
        STEP(1, 0, qA.z)     // step t+1 : prefetch token t+2
        STEP(0, 1, qA.w)     // step t+2 : prefetch token t+3
        STEP(1, 0, qB.x)     // step t+3 : prefetch token t+4

        qA = qB;  qB = qC;
    }

    if (active) out[j] = hold;
}

extern "C" void kernel_launch(void* const* d_in, const int* in_sizes, int n_in,
                              void* d_out, int out_size, void* d_ws, size_t ws_size,
                              hipStream_t stream)
{
    const int*   x    = (const int*)  d_in[0];
    const float* emb  = (const float*)d_in[1];
    const float* w_ih = (const float*)d_in[2];
    const float* w_hh = (const float*)d_in[3];
    const float* b_ih = (const float*)d_in[4];
    const float* b_hh = (const float*)d_in[5];
    float* out = (float*)d_out;

    float*    proj  = (float*)d_ws;                        // 18000 f32 = 72 KB
    _Float16* afrag = (_Float16*)(proj + VOCAB * NPROJ);   // 36864 f16 = 72 KB
    _Float16* wtail = afrag + NMFW * MT * KS * 64 * 8;     // 1200 f16 = 2.4 KB

    const int total = NMFW * MT * KS * 64 * 8;             // 36864 covers all jobs
    precompute_kernel<<<(total + 255) / 256, 256, 0, stream>>>(
        emb, w_ih, b_ih, b_hh, w_hh, proj, afrag, wtail);
    gru_seq_kernel<<<1, 256, 0, stream>>>(x, b_hh, proj, afrag, wtail, out);
}